// Round 9
// baseline (202.431 us; speedup 1.0000x reference)
//
#include <hip/hip_runtime.h>

// eTofts model: B=8, T=60, H=W=256.  MEASUREMENT ROUND.
// Kernel 1 = R4 verbatim (best so far, 33.1 us, ~4.1 TB/s true traffic).
// Kernel 2 = write-BW probe: plain dwordx4 grid-stride stores of
// hash-derived (incompressible) data to d_ws, ~2 passes (~960 MiB), at
// fill-like occupancy. Lands in rocprof top-5 so we finally SEE counters.
// Discriminates: fill's 7.09 TB/s = const-data artifact vs real write BW.

#define N_TIME 60
#define HW (256 * 256)
#define CHUNKS 4
#define CHUNK_LEN (N_TIME / CHUNKS)   // 15
#define PXB 4096                      // pixels per block (256 thr * 16 px)

typedef float f32x4 __attribute__((ext_vector_type(4)));

__global__ __launch_bounds__(256, 2) void etofts_kernel(
    const float* __restrict__ params,  // [B,3,H,W]
    const float* __restrict__ Cp,      // [B,T]
    const float* __restrict__ S0,      // [B,1,H,W]
    const float* __restrict__ T1,      // [B,1,H,W]
    float* __restrict__ out)           // [B,T,H,W]
{
    const float DT     = 5.0f;
    const float TR     = 5.0f;
    const float EPS    = 1e-8f;
    const float COS_FA = 0.9848077530122081f;            // cos(10 deg)
    const float QC2    = 0.0225f * 1.4426950408889634f;  // (R1*TR/1000)*log2(e)

    const int bx    = blockIdx.x;
    const int b     = bx >> 6;
    const int chunk = (bx >> 4) & 3;
    const int blk   = bx & 15;

    const int w    = threadIdx.x >> 6;
    const int lane = threadIdx.x & 63;
    const int pixw = blk * PXB + w * 1024 + lane * 4;

    const float* p0 = params + ((size_t)b * 3 + 0) * HW + pixw;
    const float* p1 = params + ((size_t)b * 3 + 1) * HW + pixw;
    const float* p2 = params + ((size_t)b * 3 + 2) * HW + pixw;
    const float* ps = S0 + (size_t)b * HW + pixw;
    const float* pt = T1 + (size_t)b * HW + pixw;

    float Kt[16], vp[16], decay[16], Ce[16], eP[16], Kc[16], d0[16], d1[16];

#pragma unroll
    for (int q = 0; q < 4; ++q) {
        const float4 kt4 = *reinterpret_cast<const float4*>(p0 + q * 256);
        const float4 vp4 = *reinterpret_cast<const float4*>(p1 + q * 256);
        const float4 ve4 = *reinterpret_cast<const float4*>(p2 + q * 256);
        const float4 s04 = *reinterpret_cast<const float4*>(ps + q * 256);
        const float4 t14 = *reinterpret_cast<const float4*>(pt + q * 256);
        const float ktv[4] = {kt4.x, kt4.y, kt4.z, kt4.w};
        const float vpv[4] = {vp4.x, vp4.y, vp4.z, vp4.w};
        const float vev[4] = {ve4.x, ve4.y, ve4.z, ve4.w};
        const float s0v[4] = {s04.x, s04.y, s04.z, s04.w};
        const float t1v[4] = {t14.x, t14.y, t14.z, t14.w};
#pragma unroll
        for (int i = 0; i < 4; ++i) {
            const int j = q * 4 + i;
            const float Ktrans = ktv[i] * (1.0f / 60.0f);
            const float Kep    = __fdividef(Ktrans, vev[i] + EPS);
            Kt[j]    = Ktrans;
            vp[j]    = vpv[i];
            decay[j] = __expf(-Kep * DT);
            const float P = __fdividef(TR, t1v[i] + EPS);
            const float e = __expf(-P);
            eP[j] = e;
            Kc[j] = (1.0f - COS_FA * e) * s0v[i];
            const float den1 = 1.0f - e;
            d0[j] = den1 + EPS;
            d1[j] = COS_FA * den1;
            Ce[j] = 0.0f;
        }
    }

    const float* cp_row = Cp + b * N_TIME;
    const int t0 = chunk * CHUNK_LEN;

    for (int t = 0; t < t0; ++t) {
        const float cpdt = cp_row[t] * DT;
#pragma unroll
        for (int j = 0; j < 16; ++j) Ce[j] = Ce[j] * decay[j] + cpdt;
    }

    float* outp = out + ((size_t)(b * N_TIME + t0)) * HW + pixw;

#pragma unroll
    for (int k = 0; k < CHUNK_LEN; ++k) {
        const float cp   = cp_row[t0 + k];
        const float cpdt = cp * DT;
        float* op = outp + (size_t)k * HW;
#pragma unroll
        for (int q = 0; q < 4; ++q) {
            float st[4];
#pragma unroll
            for (int i = 0; i < 4; ++i) {
                const int j = q * 4 + i;
                Ce[j] = Ce[j] * decay[j] + cpdt;
                const float Ct  = vp[j] * cp + Kt[j] * Ce[j];
                const float ePQ = eP[j] * exp2f(-QC2 * Ct);
                const float num = Kc[j] - Kc[j] * ePQ;
                const float den = d0[j] - d1[j] * ePQ;
                st[i] = __fdividef(num, den);
            }
            f32x4 v = {st[0], st[1], st[2], st[3]};
            __builtin_nontemporal_store(v, reinterpret_cast<f32x4*>(op + q * 256));
        }
    }
}

// --- Probe: fill-mimic with INCOMPRESSIBLE data, plain stores, grid-stride.
// Writes d_ws (never validated; harness poisons it anyway). ~845-1024 waves
// like the 7.09 TB/s fill. 2 passes so dur > 70 us -> visible in top-5.
__global__ __launch_bounds__(256) void ws_write_probe(
    f32x4* __restrict__ ws, unsigned long long n4, int passes)
{
    const unsigned long long stride =
        (unsigned long long)gridDim.x * blockDim.x;
    for (int p = 0; p < passes; ++p) {
        for (unsigned long long i =
                 (unsigned long long)blockIdx.x * blockDim.x + threadIdx.x;
             i < n4; i += stride) {
            // hash-derived, varies every 4 B: defeats constant/delta compression
            unsigned int h = (unsigned int)i * 2654435761u + (unsigned int)p * 97u;
            f32x4 v;
            v.x = (float)(h & 0xFFFFu);
            v.y = (float)((h >> 8) & 0xFFFFu);
            v.z = (float)((h * 3u) & 0xFFFFu);
            v.w = (float)((h ^ 0x5a5au) & 0xFFFFu);
            ws[i] = v;   // PLAIN allocating store, same as the fill kernel
        }
    }
}

extern "C" void kernel_launch(void* const* d_in, const int* in_sizes, int n_in,
                              void* d_out, int out_size, void* d_ws, size_t ws_size,
                              hipStream_t stream) {
    const float* params = (const float*)d_in[0];
    const float* Cp     = (const float*)d_in[1];
    const float* S0     = (const float*)d_in[2];
    const float* T1     = (const float*)d_in[3];
    float* out          = (float*)d_out;

    const int grid = 8 * CHUNKS * (HW / PXB);  // 512 blocks
    etofts_kernel<<<grid, 256, 0, stream>>>(params, Cp, S0, T1, out);

    // Measurement probe (deterministic, graph-safe, writes only d_ws).
    if (ws_size >= (64ull << 20)) {
        unsigned long long n4 = (unsigned long long)(ws_size / 16);
        ws_write_probe<<<256, 256, 0, stream>>>((f32x4*)d_ws, n4, 2);
    }
}

// Round 10
// 33.499 us; speedup vs baseline: 6.0430x; 6.0430x over previous
//
#include <hip/hip_runtime.h>

// eTofts model: B=8, T=60, H=W=256.
//   params[B,3,H,W], Cp[B,T], S0[B,1,H,W], T1[B,1,H,W] -> St[B,T,H,W] fp32
//
// R9 probe result (incompressible grid-stride write, plain stores):
//   5.56-5.74 TB/s, FETCH~0.  Fill's 7.09 TB/s was a constant-data artifact.
//   => real write ceiling ~5.65 TB/s; no RFO on gfx950 plain stores.
// R4 (33.1 us) actually moved 168 MB (126 wr + 42 rd: CHUNKS=4 re-reads
// inputs 4x) = 5.1 TB/s = ~90% of ceiling. Last inefficiency: kill the 42 MB
// of redundant reads. This kernel: CHUNKS=1 (inputs read ONCE, no replay),
// 8 px/thread in two 1KB-coalesced q-groups, nt stores, 256 blocks (1/CU,
// 4 waves/CU -- probe proved that saturates writes). 136 MB total.

#define N_TIME 60
#define HW (256 * 256)
#define PX 8                         // pixels per thread, 2 q-groups of 4
#define TPB 256
#define GRID 256                     // 524288 px / (256 thr * 8 px) ; 1 per CU

typedef float f32x4 __attribute__((ext_vector_type(4)));

__global__ __launch_bounds__(TPB) void etofts_kernel(
    const float* __restrict__ params,  // [B,3,H,W]
    const float* __restrict__ Cp,      // [B,T]
    const float* __restrict__ S0,      // [B,1,H,W]
    const float* __restrict__ T1,      // [B,1,H,W]
    float* __restrict__ out)           // [B,T,H,W]
{
    const float DT     = 5.0f;
    const float TR     = 5.0f;
    const float EPS    = 1e-8f;
    const float COS_FA = 0.9848077530122081f;            // cos(10 deg)
    const float QC2    = 0.0225f * 1.4426950408889634f;  // (R1*TR/1000)*log2(e)

    // 256 blocks: 32 per batch. All splits block-uniform -> Cp is s_load.
    const int bx  = blockIdx.x;
    const int b   = bx >> 5;
    const int blk = bx & 31;

    // Wave w owns a 2 KB span per frame: two 1 KB coalesced q-groups.
    const int w    = threadIdx.x >> 6;
    const int lane = threadIdx.x & 63;
    const int pixw = blk * 2048 + w * 512 + lane * 4;   // + q*256

    const float* p0 = params + ((size_t)b * 3 + 0) * HW + pixw;
    const float* p1 = params + ((size_t)b * 3 + 1) * HW + pixw;
    const float* p2 = params + ((size_t)b * 3 + 2) * HW + pixw;
    const float* ps = S0 + (size_t)b * HW + pixw;
    const float* pt = T1 + (size_t)b * HW + pixw;

    float Kt[PX], vp[PX], decay[PX], Ce[PX], eP[PX], Kc[PX], d0[PX], d1[PX];

#pragma unroll
    for (int q = 0; q < 2; ++q) {
        const float4 kt4 = *reinterpret_cast<const float4*>(p0 + q * 256);
        const float4 vp4 = *reinterpret_cast<const float4*>(p1 + q * 256);
        const float4 ve4 = *reinterpret_cast<const float4*>(p2 + q * 256);
        const float4 s04 = *reinterpret_cast<const float4*>(ps + q * 256);
        const float4 t14 = *reinterpret_cast<const float4*>(pt + q * 256);
        const float ktv[4] = {kt4.x, kt4.y, kt4.z, kt4.w};
        const float vpv[4] = {vp4.x, vp4.y, vp4.z, vp4.w};
        const float vev[4] = {ve4.x, ve4.y, ve4.z, ve4.w};
        const float s0v[4] = {s04.x, s04.y, s04.z, s04.w};
        const float t1v[4] = {t14.x, t14.y, t14.z, t14.w};
#pragma unroll
        for (int i = 0; i < 4; ++i) {
            const int j = q * 4 + i;
            const float Ktrans = ktv[i] * (1.0f / 60.0f);
            const float Kep    = __fdividef(Ktrans, vev[i] + EPS);
            Kt[j]    = Ktrans;
            vp[j]    = vpv[i];
            decay[j] = __expf(-Kep * DT);
            const float P = __fdividef(TR, t1v[i] + EPS);
            const float e = __expf(-P);
            eP[j] = e;
            Kc[j] = (1.0f - COS_FA * e) * s0v[i];
            const float den1 = 1.0f - e;
            d0[j] = den1 + EPS;              // den = d0 - d1*ePQ
            d1[j] = COS_FA * den1;
            Ce[j] = 0.0f;
        }
    }

    const float* cp_row = Cp + b * N_TIME;   // uniform -> scalar s_load
    float* outp = out + ((size_t)b * N_TIME) * HW + pixw;

#pragma unroll 4
    for (int t = 0; t < N_TIME; ++t) {
        const float cp   = cp_row[t];
        const float cpdt = cp * DT;
        float* op = outp + (size_t)t * HW;
#pragma unroll
        for (int q = 0; q < 2; ++q) {
            float st[4];
#pragma unroll
            for (int i = 0; i < 4; ++i) {
                const int j = q * 4 + i;
                Ce[j] = Ce[j] * decay[j] + cpdt;
                const float Ct  = vp[j] * cp + Kt[j] * Ce[j];
                const float ePQ = eP[j] * exp2f(-QC2 * Ct);
                const float num = Kc[j] - Kc[j] * ePQ;
                const float den = d0[j] - d1[j] * ePQ;
                st[i] = __fdividef(num, den);
            }
            f32x4 v = {st[0], st[1], st[2], st[3]};
            __builtin_nontemporal_store(v, reinterpret_cast<f32x4*>(op + q * 256));
        }
    }
}

extern "C" void kernel_launch(void* const* d_in, const int* in_sizes, int n_in,
                              void* d_out, int out_size, void* d_ws, size_t ws_size,
                              hipStream_t stream) {
    const float* params = (const float*)d_in[0];
    const float* Cp     = (const float*)d_in[1];
    const float* S0     = (const float*)d_in[2];
    const float* T1     = (const float*)d_in[3];
    float* out          = (float*)d_out;

    etofts_kernel<<<GRID, TPB, 0, stream>>>(params, Cp, S0, T1, out);
}

// Round 11
// 31.098 us; speedup vs baseline: 6.5095x; 1.0772x over previous
//
#include <hip/hip_runtime.h>

// eTofts model: B=8, T=60, H=W=256.
//   params[B,3,H,W], Cp[B,T], S0[B,1,H,W], T1[B,1,H,W] -> St[B,T,H,W] fp32
//
// Session knowledge:
//  - Incompressible pure-write ceiling (R9 probe, plain dwordx4 grid-stride):
//    5.65 TB/s. Fill kernel's 7.09 TB/s is a constant-data artifact. FETCH~0
//    => no RFO on plain or nt full-line stores.
//  - Effective-BW table: R4 (16px, 8 waves/CU, nt, 4KB burst) = 5.08 TB/s;
//    R10 (8px, 4 waves/CU, nt, 2KB) = 4.06; scalar-store 256B granule = 3.57.
//    => mixed compute+store efficiency scales with waves/CU and burst size.
//  - CHUNKS=1 minimizes traffic (136 MB: inputs read once, no replay).
// R11 = R10 + occupancy 4->8 waves/CU: 512 blocks x 256 thr x 4 px.

#define N_TIME 60
#define HW (256 * 256)
#define TPB 256
#define GRID 512                     // 2 blocks/CU -> 8 waves/CU

typedef float f32x4 __attribute__((ext_vector_type(4)));

__global__ __launch_bounds__(TPB) void etofts_kernel(
    const float* __restrict__ params,  // [B,3,H,W]
    const float* __restrict__ Cp,      // [B,T]
    const float* __restrict__ S0,      // [B,1,H,W]
    const float* __restrict__ T1,      // [B,1,H,W]
    float* __restrict__ out)           // [B,T,H,W]
{
    const float DT     = 5.0f;
    const float TR     = 5.0f;
    const float EPS    = 1e-8f;
    const float COS_FA = 0.9848077530122081f;            // cos(10 deg)
    const float QC2    = 0.0225f * 1.4426950408889634f;  // (R1*TR/1000)*log2(e)

    // 512 blocks: 64 per batch. All splits block-uniform -> Cp is s_load.
    const int bx  = blockIdx.x;
    const int b   = bx >> 6;
    const int blk = bx & 63;

    // Wave w writes one 1 KB contiguous span per frame.
    const int w    = threadIdx.x >> 6;
    const int lane = threadIdx.x & 63;
    const int pixw = blk * 1024 + w * 256 + lane * 4;

    const size_t plane = (size_t)b * HW + pixw;

    const float4 kt4 = *reinterpret_cast<const float4*>(params + ((size_t)b * 3 + 0) * HW + pixw);
    const float4 vp4 = *reinterpret_cast<const float4*>(params + ((size_t)b * 3 + 1) * HW + pixw);
    const float4 ve4 = *reinterpret_cast<const float4*>(params + ((size_t)b * 3 + 2) * HW + pixw);
    const float4 s04 = *reinterpret_cast<const float4*>(S0 + plane);
    const float4 t14 = *reinterpret_cast<const float4*>(T1 + plane);

    float Kt[4], vp[4], decay[4], Ce[4], eP[4], Kc[4], d0[4], d1[4];
    {
        const float ktv[4] = {kt4.x, kt4.y, kt4.z, kt4.w};
        const float vpv[4] = {vp4.x, vp4.y, vp4.z, vp4.w};
        const float vev[4] = {ve4.x, ve4.y, ve4.z, ve4.w};
        const float s0v[4] = {s04.x, s04.y, s04.z, s04.w};
        const float t1v[4] = {t14.x, t14.y, t14.z, t14.w};
#pragma unroll
        for (int i = 0; i < 4; ++i) {
            const float Ktrans = ktv[i] * (1.0f / 60.0f);
            const float Kep    = __fdividef(Ktrans, vev[i] + EPS);
            Kt[i]    = Ktrans;
            vp[i]    = vpv[i];
            decay[i] = __expf(-Kep * DT);
            const float P = __fdividef(TR, t1v[i] + EPS);
            const float e = __expf(-P);
            eP[i] = e;
            Kc[i] = (1.0f - COS_FA * e) * s0v[i];
            const float den1 = 1.0f - e;
            d0[i] = den1 + EPS;              // den = d0 - d1*ePQ
            d1[i] = COS_FA * den1;
            Ce[i] = 0.0f;
        }
    }

    const float* cp_row = Cp + b * N_TIME;   // uniform -> scalar s_load
    float* outp = out + ((size_t)b * N_TIME) * HW + pixw;

#pragma unroll 4
    for (int t = 0; t < N_TIME; ++t) {
        const float cp   = cp_row[t];
        const float cpdt = cp * DT;
        float st[4];
#pragma unroll
        for (int i = 0; i < 4; ++i) {
            Ce[i] = Ce[i] * decay[i] + cpdt;
            const float Ct  = vp[i] * cp + Kt[i] * Ce[i];
            const float ePQ = eP[i] * exp2f(-QC2 * Ct);
            const float num = Kc[i] - Kc[i] * ePQ;
            const float den = d0[i] - d1[i] * ePQ;
            st[i] = __fdividef(num, den);
        }
        f32x4 v = {st[0], st[1], st[2], st[3]};
        __builtin_nontemporal_store(v, reinterpret_cast<f32x4*>(outp + (size_t)t * HW));
    }
}

extern "C" void kernel_launch(void* const* d_in, const int* in_sizes, int n_in,
                              void* d_out, int out_size, void* d_ws, size_t ws_size,
                              hipStream_t stream) {
    const float* params = (const float*)d_in[0];
    const float* Cp     = (const float*)d_in[1];
    const float* S0     = (const float*)d_in[2];
    const float* T1     = (const float*)d_in[3];
    float* out          = (float*)d_out;

    etofts_kernel<<<GRID, TPB, 0, stream>>>(params, Cp, S0, T1, out);
}